// Round 16
// baseline (60.715 us; speedup 1.0000x reference)
//
#include <hip/hip_runtime.h>

namespace {
constexpr int N   = 1024;
constexpr int D   = 128;
constexpr int E   = 32768;
constexpr int CAP = 128;    // bucket capacity per node; P(overflow) ~ 0 (16 sigma)

using short8  = __attribute__((ext_vector_type(8))) short;
using floatx4 = __attribute__((ext_vector_type(4))) float;

__device__ __forceinline__ unsigned short f2bf(float f){
  unsigned int u = __float_as_uint(f);
  unsigned int r = (u + 0x7FFFu + ((u >> 16) & 1u)) >> 16;   // RTN-even
  return (unsigned short)r;
}
__device__ __forceinline__ float bf2f(unsigned short b){
  return __uint_as_float(((unsigned int)b) << 16);
}
// 8 consecutive f32 -> bf16x8 fragment (A-side only)
__device__ __forceinline__ short8 ldfrag(const float* p){
  float4 a = *(const float4*)p;
  float4 b = *(const float4*)(p + 4);
  short8 r;
  r[0]=(short)f2bf(a.x); r[1]=(short)f2bf(a.y); r[2]=(short)f2bf(a.z); r[3]=(short)f2bf(a.w);
  r[4]=(short)f2bf(b.x); r[5]=(short)f2bf(b.y); r[6]=(short)f2bf(b.z); r[7]=(short)f2bf(b.w);
  return r;
}

// ---- zero accumulators (block 0) + pre-convert weights to bf16 (blocks 1..128) ----
__global__ __launch_bounds__(256) void k_zero(
    int* __restrict__ cnt, int* __restrict__ srcdeg,
    const float* __restrict__ Wl, const float* __restrict__ Wr,
    const float* __restrict__ Wd, const float* __restrict__ W1,
    const float* __restrict__ Wp,
    unsigned short* __restrict__ wlb, unsigned short* __restrict__ wrb,
    unsigned short* __restrict__ wdb, unsigned short* __restrict__ w1b,
    unsigned short* __restrict__ wpb)
{
  int t = threadIdx.x, b = blockIdx.x;
  if(b == 0){
    ((int4*)cnt)[t]    = make_int4(0,0,0,0);
    ((int4*)srcdeg)[t] = make_int4(0,0,0,0);
    return;
  }
  const int T = 16384*3 + 4096 + 65536;   // 118784
  int stride = 128*256;
  for(int i = (b-1)*256 + t; i < T; i += stride){
    float v; unsigned short* dst;
    if(i < 16384){            v = Wl[i];          dst = &wlb[i]; }
    else if(i < 32768){       v = Wr[i-16384];    dst = &wrb[i-16384]; }
    else if(i < 49152){       v = Wd[i-32768];    dst = &wdb[i-32768]; }
    else if(i < 53248){       v = W1[i-49152];    dst = &w1b[i-49152]; }
    else {                    v = Wp[i-53248];    dst = &wpb[i-53248]; }
    *dst = f2bf(v);
  }
}

// ---- single edge pass: bucket fill (capacity CAP) + counts + src-degrees ----
__global__ void k_edges(const int* __restrict__ ei, int* __restrict__ cnt,
                        int* __restrict__ srcdeg, int* __restrict__ bucket){
  int e = blockIdx.x*256 + threadIdx.x;
  if(e < E){
    int s = ei[e], d = ei[E+e];
    int slot = atomicAdd(&cnt[d], 1);
    if(slot < CAP) bucket[d*CAP + slot] = s;
    atomicAdd(&srcdeg[s], 1);
  }
}

// ---- neighbor mean: 1024 blocks x 512 thr, 1 node/block, 4-way split gather ----
__global__ __launch_bounds__(512) void k_mean(const float* __restrict__ x,
    const int* __restrict__ cnt, const int* __restrict__ bucket,
    float* __restrict__ mean, float* __restrict__ s1, float* __restrict__ s2){
  __shared__ float sacc[3][128];
  int t = threadIdx.x;
  int n = blockIdx.x;
  if(n == 0 && t < D){ s1[t] = 0.f; s2[t] = 0.f; }   // consumed only by k_g12
  int f = t & 127, j2 = t >> 7;       // quarter 0..3
  int c0 = cnt[n];
  int c = c0 < CAP ? c0 : CAP;
  const int* bk = bucket + n*CAP;
  int ch = (c + 3) >> 2;
  int beg = j2 * ch, end = beg + ch < c ? beg + ch : c;
  float a0=0.f, a1=0.f, a2=0.f, a3=0.f;
  int j = beg;
  for(; j+3 < end; j += 4){
    int i0=bk[j], i1=bk[j+1], i2=bk[j+2], i3=bk[j+3];
    a0 += x[i0*D+f]; a1 += x[i1*D+f]; a2 += x[i2*D+f]; a3 += x[i3*D+f];
  }
  for(; j < end; ++j) a0 += x[bk[j]*D+f];
  float part = (a0+a1)+(a2+a3);
  if(j2 > 0) sacc[j2-1][f] = part;
  __syncthreads();
  if(j2 == 0){
    float tot = part + sacc[0][f] + sacc[1][f] + sacc[2][f];
    mean[n*D + f] = tot / (float)(c0 > 1 ? c0 : 1);
  }
}

// ============ MFMA tile kernels: 1 wave per 16x16 output tile ============
// Frags: A row = lane&15, B col = lane&15, k = (lane>>4)*8 + i. C/D: col =
// lane&15, row = (lane>>4)*4 + reg. B-operands pre-converted bf16.

// ---- G1+G2 merged: each block recomputes its strip's xg (64 MFMAs, weights
// hot in L2), stages via LDS (C/D -> A-frag transpose), then does its G2 tile.
// Grid: 64 strips x 25 tiles (8 dr | 8 Cs->S1/S2 | 8 res | 1 scores).
__global__ __launch_bounds__(64) void k_g12(
    const float* __restrict__ x, const float* __restrict__ mean,
    const unsigned short* __restrict__ wlb, const float* __restrict__ bl,
    const unsigned short* __restrict__ wrb,
    const unsigned short* __restrict__ wpb, const unsigned short* __restrict__ w1b,
    const float* __restrict__ b1, const float* __restrict__ W2,
    const float* __restrict__ b2,
    const int* __restrict__ cnt, const int* __restrict__ srcdeg,
    unsigned short* __restrict__ dr, float* __restrict__ res,
    float* __restrict__ s1, float* __restrict__ s2,
    float* __restrict__ scores)
{
  __shared__ unsigned short sxg[16][136];   // bf16 bits; 272B rows -> 2-way banks
  int bid = blockIdx.x;
  int strip = bid / 25, tt = bid - strip*25;
  int l = threadIdx.x, lr = l & 15, lg = l >> 4;
  int r0 = strip*16;

  // ---- G1 recompute for the whole strip ----
  short8 am[4], ax[4];
  const float* mrow = mean + (size_t)(r0+lr)*D + lg*8;
  const float* xrow = x    + (size_t)(r0+lr)*D + lg*8;
  #pragma unroll
  for(int s = 0; s < 4; ++s){ am[s] = ldfrag(mrow + s*32); ax[s] = ldfrag(xrow + s*32); }
  #pragma unroll
  for(int ct = 0; ct < 8; ++ct){
    const unsigned short* wl = wlb + (size_t)(ct*16+lr)*D + lg*8;
    const unsigned short* wr = wrb + (size_t)(ct*16+lr)*D + lg*8;
    floatx4 acc = {0.f,0.f,0.f,0.f};
    #pragma unroll
    for(int s = 0; s < 4; ++s) acc = __builtin_amdgcn_mfma_f32_16x16x32_bf16(am[s], *(const short8*)(wl + s*32), acc, 0,0,0);
    #pragma unroll
    for(int s = 0; s < 4; ++s) acc = __builtin_amdgcn_mfma_f32_16x16x32_bf16(ax[s], *(const short8*)(wr + s*32), acc, 0,0,0);
    int col = ct*16 + lr;
    float blv = bl[col];
    #pragma unroll
    for(int rg = 0; rg < 4; ++rg){
      int row = lg*4 + rg;
      float v = acc[rg] + blv + x[(size_t)(r0+row)*D + col];
      float g = 0.5f*v*(1.0f + erff(v*0.7071067811865475f));
      sxg[row][col] = f2bf(g);
    }
  }
  __syncthreads();   // single wave: forces lgkmcnt drain before transpose reads

  short8 ag[4];
  #pragma unroll
  for(int s = 0; s < 4; ++s) ag[s] = *(const short8*)&sxg[lr][s*32 + lg*8];

  // ---- G2 tile ----
  if(tt < 24){
    int seg = tt >> 3, ctl = tt & 7;       // seg: 0=dr,1=Cs,2=res
    int wrow = (seg == 0) ? ctl*16 : (seg == 1) ? (2*D + ctl*16) : (3*D + ctl*16);
    const unsigned short* bp = wpb + (size_t)(wrow + lr)*D + lg*8;
    floatx4 acc = {0.f,0.f,0.f,0.f};
    #pragma unroll
    for(int s = 0; s < 4; ++s) acc = __builtin_amdgcn_mfma_f32_16x16x32_bf16(ag[s], *(const short8*)(bp + s*32), acc, 0,0,0);
    if(seg == 0){
      int col = ctl*16 + lr;
      #pragma unroll
      for(int rg = 0; rg < 4; ++rg) dr[(size_t)(r0+lg*4+rg)*D + col] = f2bf(acc[rg]);
    } else if(seg == 1){
      int h = ctl*16 + lr;
      float ls1 = 0.f, ls2 = 0.f;
      #pragma unroll
      for(int rg = 0; rg < 4; ++rg){
        float c = acc[rg];
        ls1 += bf2f(sxg[lg*4+rg][h]) * c;
        ls2 += c;
      }
      ls1 += __shfl_xor(ls1, 16); ls1 += __shfl_xor(ls1, 32);
      ls2 += __shfl_xor(ls2, 16); ls2 += __shfl_xor(ls2, 32);
      if(lg == 0){ atomicAdd(&s1[h], ls1); atomicAdd(&s2[h], ls2); }
    } else {
      int col = ctl*16 + lr;
      #pragma unroll
      for(int rg = 0; rg < 4; ++rg) res[(size_t)(r0+lg*4+rg)*D + col] = acc[rg];
    }
  } else {
    floatx4 sa0 = {0.f,0.f,0.f,0.f}, sa1 = {0.f,0.f,0.f,0.f};
    const unsigned short* w10 = w1b + (size_t)(lr)*D + lg*8;
    const unsigned short* w11 = w1b + (size_t)(16+lr)*D + lg*8;
    #pragma unroll
    for(int s = 0; s < 4; ++s){
      sa0 = __builtin_amdgcn_mfma_f32_16x16x32_bf16(ag[s], *(const short8*)(w10 + s*32), sa0, 0,0,0);
      sa1 = __builtin_amdgcn_mfma_f32_16x16x32_bf16(ag[s], *(const short8*)(w11 + s*32), sa1, 0,0,0);
    }
    float b10 = b1[lr], b11 = b1[16+lr];
    float w20 = W2[lr], w21 = W2[16+lr];
    #pragma unroll
    for(int rg = 0; rg < 4; ++rg){
      float v = fmaxf(sa0[rg] + b10, 0.f)*w20 + fmaxf(sa1[rg] + b11, 0.f)*w21;
      v += __shfl_xor(v, 1); v += __shfl_xor(v, 2);
      v += __shfl_xor(v, 4); v += __shfl_xor(v, 8);
      if(lr == 0){
        int row = r0 + lg*4 + rg;
        scores[row] = v + b2[0] + (float)(cnt[row] + srcdeg[row]);
      }
    }
  }
}

// ---- G3 + rank merged (both depend only on g12) ----
__global__ __launch_bounds__(64) void k_g3rank(
    const unsigned short* __restrict__ dr,
    const unsigned short* __restrict__ wdb, const float* __restrict__ bd,
    float* __restrict__ delta,
    const float* __restrict__ scores, int* __restrict__ sidx)
{
  int bid = blockIdx.x;
  int l = threadIdx.x;
  if(bid < 512){
    int strip = bid >> 3, ct = bid & 7;
    int lr = l & 15, lg = l >> 4;
    int r0 = strip*16;
    const unsigned short* adp = dr + (size_t)(r0+lr)*D + lg*8;
    short8 ad[4];
    #pragma unroll
    for(int s = 0; s < 4; ++s) ad[s] = *(const short8*)(adp + s*32);
    const unsigned short* wd = wdb + (size_t)(ct*16+lr)*D + lg*8;
    floatx4 acc = {0.f,0.f,0.f,0.f};
    #pragma unroll
    for(int s = 0; s < 4; ++s) acc = __builtin_amdgcn_mfma_f32_16x16x32_bf16(ad[s], *(const short8*)(wd + s*32), acc, 0,0,0);
    int col = ct*16 + lr;
    float bdv = bd[col];
    #pragma unroll
    for(int rg = 0; rg < 4; ++rg){
      float d2 = acc[rg] + bdv;
      float sp = (d2 > 20.f) ? d2 : log1pf(expf(d2));
      delta[(size_t)(r0+lg*4+rg)*D + col] = sp;
    }
  } else {
    int i = bid - 512;
    float si = scores[i];
    int c = 0;
    #pragma unroll
    for(int ch = 0; ch < 4; ++ch){
      float4 sj = *(const float4*)&scores[l*4 + ch*256];
      #pragma unroll
      for(int k = 0; k < 4; ++k){
        int j = l*4 + ch*256 + k;
        float s = (k==0)?sj.x:(k==1)?sj.y:(k==2)?sj.z:sj.w;
        c += (s > si || (s == si && j < i)) ? 1 : 0;
      }
    }
    #pragma unroll
    for(int m = 1; m < 64; m <<= 1) c += __shfl_xor(c, m);
    if(l == 0) sidx[c] = i;
  }
}

// ---- cumsum over sorted order: 128 blocks, 1 head/block ----
__global__ __launch_bounds__(1024) void k_cumsum(const float* __restrict__ delta,
     const int* __restrict__ sidx, const float* __restrict__ Bp, float* __restrict__ pfx){
  int t = threadIdx.x, h = blockIdx.x;
  int i = sidx[t];
  float v = delta[(size_t)i*D + h] * Bp[h];
  int lane = t & 63, w = t >> 6;
  #pragma unroll
  for(int o2 = 1; o2 < 64; o2 <<= 1){
    float nb = __shfl_up(v, o2, 64);
    if(lane >= o2) v += nb;
  }
  __shared__ float wsum[16];
  if(lane == 63) wsum[w] = v;
  __syncthreads();
  float pref = 0.f;
  #pragma unroll
  for(int i2 = 0; i2 < 16; ++i2){
    float s = wsum[i2];
    if(i2 < w) pref += s;
  }
  pfx[(size_t)t*D + h] = v + pref;
}

// ---- final: 512 blocks x 256 thr, 2 sorted rows/block; LN + un-permute ----
__global__ __launch_bounds__(256) void k_final(
    const float* __restrict__ delta, const float* __restrict__ res,
    const float* __restrict__ pfx, const int* __restrict__ sidx,
    const float* __restrict__ s1, const float* __restrict__ s2,
    const float* __restrict__ A, const float* __restrict__ Bp,
    const float* __restrict__ Dp, const float* __restrict__ x,
    float* __restrict__ out){
  int b = blockIdx.x, t = threadIdx.x;
  int half = t >> 7, hh = t & 127;
  int l = b*2 + half;
  int i = sidx[l];
  float dlt = delta[(size_t)i*D + hh];
  float dAv = expf(dlt * A[hh]) * Bp[hh];
  float o = dAv * s1[hh] + pfx[(size_t)l*D + hh] * s2[hh] + res[(size_t)i*D + hh] * Dp[0];
  __shared__ float fm[2][2], fv[2][2];
  float v = o;
  v += __shfl_down(v, 32); v += __shfl_down(v, 16); v += __shfl_down(v, 8);
  v += __shfl_down(v, 4);  v += __shfl_down(v, 2);  v += __shfl_down(v, 1);
  int wid = (t >> 6) & 1;
  if((t & 63) == 0) fm[half][wid] = v;
  __syncthreads();
  float mean = (fm[half][0] + fm[half][1]) * (1.0f/128.0f);
  float cd = o - mean;
  float cv = cd*cd;
  cv += __shfl_down(cv, 32); cv += __shfl_down(cv, 16); cv += __shfl_down(cv, 8);
  cv += __shfl_down(cv, 4);  cv += __shfl_down(cv, 2);  cv += __shfl_down(cv, 1);
  if((t & 63) == 0) fv[half][wid] = cv;
  __syncthreads();
  float var = (fv[half][0] + fv[half][1]) * (1.0f/128.0f);
  out[(size_t)i*D + hh] = x[(size_t)i*D + hh] + cd * rsqrtf(var + 1e-5f);
}

} // namespace

extern "C" void kernel_launch(void* const* d_in, const int* in_sizes, int n_in,
                              void* d_out, int out_size, void* d_ws, size_t ws_size,
                              hipStream_t stream){
  const float* x   = (const float*)d_in[0];
  const int*   ei  = (const int*)d_in[1];
  const float* Wl  = (const float*)d_in[2];
  const float* bl  = (const float*)d_in[3];
  const float* Wr  = (const float*)d_in[4];
  const float* W1  = (const float*)d_in[5];
  const float* b1  = (const float*)d_in[6];
  const float* W2  = (const float*)d_in[7];
  const float* b2  = (const float*)d_in[8];
  const float* Wp  = (const float*)d_in[9];
  const float* A   = (const float*)d_in[10];
  const float* Bp  = (const float*)d_in[11];
  const float* Dp  = (const float*)d_in[12];
  const float* Wd  = (const float*)d_in[13];
  const float* bd  = (const float*)d_in[14];

  char* ws = (char*)d_ws;
  size_t o = 0;
  auto alloc = [&](size_t bytes)->char*{
    char* p = ws + o;
    o = (o + bytes + 255) & ~(size_t)255;
    return p;
  };
  float* s1     = (float*)alloc(D*4);
  float* s2     = (float*)alloc(D*4);
  int*   cnt    = (int*)  alloc(N*4);
  int*   srcdeg = (int*)  alloc(N*4);
  int*   bucket = (int*)  alloc((size_t)N*CAP*4);
  float* meanb  = (float*)alloc((size_t)N*D*4);
  unsigned short* dr  = (unsigned short*)alloc((size_t)N*D*2);
  unsigned short* wlb = (unsigned short*)alloc((size_t)D*D*2);
  unsigned short* wrb = (unsigned short*)alloc((size_t)D*D*2);
  unsigned short* wdb = (unsigned short*)alloc((size_t)D*D*2);
  unsigned short* w1b = (unsigned short*)alloc((size_t)32*D*2);
  unsigned short* wpb = (unsigned short*)alloc((size_t)4*D*D*2);
  float* scores = (float*)alloc(N*4);
  int*   sidx   = (int*)  alloc(N*4);
  float* delta  = (float*)alloc((size_t)N*D*4);
  float* res    = (float*)alloc((size_t)N*D*4);
  float* pfx    = (float*)alloc((size_t)N*D*4);
  (void)ws_size; (void)in_sizes; (void)n_in; (void)out_size;

  k_zero  <<<129, 256, 0, stream>>>(cnt, srcdeg, Wl, Wr, Wd, W1, Wp, wlb, wrb, wdb, w1b, wpb);
  k_edges <<<(E+255)/256, 256, 0, stream>>>(ei, cnt, srcdeg, bucket);
  k_mean  <<<N, 512, 0, stream>>>(x, cnt, bucket, meanb, s1, s2);
  k_g12   <<<64*25, 64, 0, stream>>>(x, meanb, wlb, bl, wrb, wpb, w1b, b1, W2, b2,
                                     cnt, srcdeg, dr, res, s1, s2, scores);
  k_g3rank<<<512+1024, 64, 0, stream>>>(dr, wdb, bd, delta, scores, sidx);
  k_cumsum<<<D, 1024, 0, stream>>>(delta, sidx, Bp, pfx);
  k_final <<<N/2, 256, 0, stream>>>(delta, res, pfx, sidx, s1, s2, A, Bp, Dp, x, (float*)d_out);
}

// Round 17
// 48.978 us; speedup vs baseline: 1.2396x; 1.2396x over previous
//
#include <hip/hip_runtime.h>

namespace {
constexpr int N   = 1024;
constexpr int D   = 128;
constexpr int E   = 32768;
constexpr int CAP = 128;    // bucket capacity per node; P(overflow) ~ 0 (16 sigma)

using short8  = __attribute__((ext_vector_type(8))) short;
using floatx4 = __attribute__((ext_vector_type(4))) float;

__device__ __forceinline__ unsigned short f2bf(float f){
  unsigned int u = __float_as_uint(f);
  unsigned int r = (u + 0x7FFFu + ((u >> 16) & 1u)) >> 16;   // RTN-even
  return (unsigned short)r;
}
__device__ __forceinline__ float bf2f(unsigned short b){
  return __uint_as_float(((unsigned int)b) << 16);
}
// 8 consecutive f32 -> bf16x8 fragment (A-side only)
__device__ __forceinline__ short8 ldfrag(const float* p){
  float4 a = *(const float4*)p;
  float4 b = *(const float4*)(p + 4);
  short8 r;
  r[0]=(short)f2bf(a.x); r[1]=(short)f2bf(a.y); r[2]=(short)f2bf(a.z); r[3]=(short)f2bf(a.w);
  r[4]=(short)f2bf(b.x); r[5]=(short)f2bf(b.y); r[6]=(short)f2bf(b.z); r[7]=(short)f2bf(b.w);
  return r;
}

// ---- zero accumulators (block 0) + pre-convert weights to bf16 (blocks 1..128) ----
__global__ __launch_bounds__(256) void k_zero(
    int* __restrict__ cnt, int* __restrict__ srcdeg,
    const float* __restrict__ Wl, const float* __restrict__ Wr,
    const float* __restrict__ Wd, const float* __restrict__ W1,
    const float* __restrict__ Wp,
    unsigned short* __restrict__ wlb, unsigned short* __restrict__ wrb,
    unsigned short* __restrict__ wdb, unsigned short* __restrict__ w1b,
    unsigned short* __restrict__ wpb)
{
  int t = threadIdx.x, b = blockIdx.x;
  if(b == 0){
    ((int4*)cnt)[t]    = make_int4(0,0,0,0);
    ((int4*)srcdeg)[t] = make_int4(0,0,0,0);
    return;
  }
  const int T = 16384*3 + 4096 + 65536;   // 118784
  int stride = 128*256;
  for(int i = (b-1)*256 + t; i < T; i += stride){
    float v; unsigned short* dst;
    if(i < 16384){            v = Wl[i];          dst = &wlb[i]; }
    else if(i < 32768){       v = Wr[i-16384];    dst = &wrb[i-16384]; }
    else if(i < 49152){       v = Wd[i-32768];    dst = &wdb[i-32768]; }
    else if(i < 53248){       v = W1[i-49152];    dst = &w1b[i-49152]; }
    else {                    v = Wp[i-53248];    dst = &wpb[i-53248]; }
    *dst = f2bf(v);
  }
}

// ---- single edge pass: bucket fill (capacity CAP) + counts + src-degrees ----
__global__ void k_edges(const int* __restrict__ ei, int* __restrict__ cnt,
                        int* __restrict__ srcdeg, int* __restrict__ bucket){
  int e = blockIdx.x*256 + threadIdx.x;
  if(e < E){
    int s = ei[e], d = ei[E+e];
    int slot = atomicAdd(&cnt[d], 1);
    if(slot < CAP) bucket[d*CAP + slot] = s;
    atomicAdd(&srcdeg[s], 1);
  }
}

// ---- neighbor mean: 1024 blocks x 512 thr, 1 node/block, 4-way split gather ----
__global__ __launch_bounds__(512) void k_mean(const float* __restrict__ x,
    const int* __restrict__ cnt, const int* __restrict__ bucket,
    float* __restrict__ mean, float* __restrict__ s1, float* __restrict__ s2){
  __shared__ float sacc[3][128];
  int t = threadIdx.x;
  int n = blockIdx.x;
  if(n == 0 && t < D){ s1[t] = 0.f; s2[t] = 0.f; }   // consumed only by k_g2
  int f = t & 127, j2 = t >> 7;       // quarter 0..3
  int c0 = cnt[n];
  int c = c0 < CAP ? c0 : CAP;
  const int* bk = bucket + n*CAP;
  int ch = (c + 3) >> 2;
  int beg = j2 * ch, end = beg + ch < c ? beg + ch : c;
  float a0=0.f, a1=0.f, a2=0.f, a3=0.f;
  int j = beg;
  for(; j+3 < end; j += 4){
    int i0=bk[j], i1=bk[j+1], i2=bk[j+2], i3=bk[j+3];
    a0 += x[i0*D+f]; a1 += x[i1*D+f]; a2 += x[i2*D+f]; a3 += x[i3*D+f];
  }
  for(; j < end; ++j) a0 += x[bk[j]*D+f];
  float part = (a0+a1)+(a2+a3);
  if(j2 > 0) sacc[j2-1][f] = part;
  __syncthreads();
  if(j2 == 0){
    float tot = part + sacc[0][f] + sacc[1][f] + sacc[2][f];
    mean[n*D + f] = tot / (float)(c0 > 1 ? c0 : 1);
  }
}

// ============ MFMA tile kernels: 1 wave per 16x16 output tile ============
// Frags: A row = lane&15, B col = lane&15, k = (lane>>4)*8 + i. C/D: col =
// lane&15, row = (lane>>4)*4 + reg. B-operands pre-converted bf16.

// ---- G1: xg = gelu(mean@Wl^T + x@Wr^T + bl + x), bf16 out ----
__global__ __launch_bounds__(64) void k_g1(
    const float* __restrict__ x, const float* __restrict__ mean,
    const unsigned short* __restrict__ wlb, const float* __restrict__ bl,
    const unsigned short* __restrict__ wrb, unsigned short* __restrict__ xg)
{
  int bid = blockIdx.x;             // 64 strips x 8 col-tiles
  int strip = bid >> 3, ct = bid & 7;
  int l = threadIdx.x, lr = l & 15, lg = l >> 4;
  int r0 = strip*16;

  const float* mrow = mean + (size_t)(r0+lr)*D + lg*8;
  const float* xrow = x    + (size_t)(r0+lr)*D + lg*8;
  short8 am[4], ax[4];
  #pragma unroll
  for(int s = 0; s < 4; ++s){ am[s] = ldfrag(mrow + s*32); ax[s] = ldfrag(xrow + s*32); }

  const unsigned short* wl = wlb + (size_t)(ct*16+lr)*D + lg*8;
  const unsigned short* wr = wrb + (size_t)(ct*16+lr)*D + lg*8;
  floatx4 acc = {0.f,0.f,0.f,0.f};
  #pragma unroll
  for(int s = 0; s < 4; ++s) acc = __builtin_amdgcn_mfma_f32_16x16x32_bf16(am[s], *(const short8*)(wl + s*32), acc, 0,0,0);
  #pragma unroll
  for(int s = 0; s < 4; ++s) acc = __builtin_amdgcn_mfma_f32_16x16x32_bf16(ax[s], *(const short8*)(wr + s*32), acc, 0,0,0);

  int col = ct*16 + lr;
  float blv = bl[col];
  #pragma unroll
  for(int rg = 0; rg < 4; ++rg){
    int row = lg*4 + rg;
    float v = acc[rg] + blv + x[(size_t)(r0+row)*D + col];
    float g = 0.5f*v*(1.0f + erff(v*0.7071067811865475f));
    xg[(size_t)(r0+row)*D + col] = f2bf(g);
  }
}

// ---- G2: 25 tiles/strip: 8 dr | 8 Cs->S1/S2 | 8 res | 1 scores ----
__global__ __launch_bounds__(64) void k_g2(
    const unsigned short* __restrict__ xg,
    const unsigned short* __restrict__ wpb, const unsigned short* __restrict__ w1b,
    const float* __restrict__ b1, const float* __restrict__ W2,
    const float* __restrict__ b2,
    const int* __restrict__ cnt, const int* __restrict__ srcdeg,
    unsigned short* __restrict__ dr, float* __restrict__ res,
    float* __restrict__ s1, float* __restrict__ s2,
    float* __restrict__ scores)
{
  int bid = blockIdx.x;             // 64 strips x 25 tiles
  int strip = bid / 25, tt = bid - strip*25;
  int l = threadIdx.x, lr = l & 15, lg = l >> 4;
  int r0 = strip*16;

  const unsigned short* agp = xg + (size_t)(r0+lr)*D + lg*8;
  short8 ag[4];
  #pragma unroll
  for(int s = 0; s < 4; ++s) ag[s] = *(const short8*)(agp + s*32);

  if(tt < 24){
    int seg = tt >> 3, ctl = tt & 7;       // seg: 0=dr,1=Cs,2=res
    int wrow = (seg == 0) ? ctl*16 : (seg == 1) ? (2*D + ctl*16) : (3*D + ctl*16);
    const unsigned short* bp = wpb + (size_t)(wrow + lr)*D + lg*8;
    floatx4 acc = {0.f,0.f,0.f,0.f};
    #pragma unroll
    for(int s = 0; s < 4; ++s) acc = __builtin_amdgcn_mfma_f32_16x16x32_bf16(ag[s], *(const short8*)(bp + s*32), acc, 0,0,0);
    if(seg == 0){
      int col = ctl*16 + lr;
      #pragma unroll
      for(int rg = 0; rg < 4; ++rg) dr[(size_t)(r0+lg*4+rg)*D + col] = f2bf(acc[rg]);
    } else if(seg == 1){
      int h = ctl*16 + lr;
      float ls1 = 0.f, ls2 = 0.f;
      #pragma unroll
      for(int rg = 0; rg < 4; ++rg){
        float c = acc[rg];
        ls1 += bf2f(xg[(size_t)(r0+lg*4+rg)*D + h]) * c;
        ls2 += c;
      }
      ls1 += __shfl_xor(ls1, 16); ls1 += __shfl_xor(ls1, 32);
      ls2 += __shfl_xor(ls2, 16); ls2 += __shfl_xor(ls2, 32);
      if(lg == 0){ atomicAdd(&s1[h], ls1); atomicAdd(&s2[h], ls2); }
    } else {
      int col = ctl*16 + lr;
      #pragma unroll
      for(int rg = 0; rg < 4; ++rg) res[(size_t)(r0+lg*4+rg)*D + col] = acc[rg];
    }
  } else {
    floatx4 sa0 = {0.f,0.f,0.f,0.f}, sa1 = {0.f,0.f,0.f,0.f};
    const unsigned short* w10 = w1b + (size_t)(lr)*D + lg*8;
    const unsigned short* w11 = w1b + (size_t)(16+lr)*D + lg*8;
    #pragma unroll
    for(int s = 0; s < 4; ++s){
      sa0 = __builtin_amdgcn_mfma_f32_16x16x32_bf16(ag[s], *(const short8*)(w10 + s*32), sa0, 0,0,0);
      sa1 = __builtin_amdgcn_mfma_f32_16x16x32_bf16(ag[s], *(const short8*)(w11 + s*32), sa1, 0,0,0);
    }
    float b10 = b1[lr], b11 = b1[16+lr];
    float w20 = W2[lr], w21 = W2[16+lr];
    #pragma unroll
    for(int rg = 0; rg < 4; ++rg){
      float v = fmaxf(sa0[rg] + b10, 0.f)*w20 + fmaxf(sa1[rg] + b11, 0.f)*w21;
      v += __shfl_xor(v, 1); v += __shfl_xor(v, 2);
      v += __shfl_xor(v, 4); v += __shfl_xor(v, 8);
      if(lr == 0){
        int row = r0 + lg*4 + rg;
        scores[row] = v + b2[0] + (float)(cnt[row] + srcdeg[row]);
      }
    }
  }
}

// ---- G3 + rank merged (both depend only on g2) ----
__global__ __launch_bounds__(64) void k_g3rank(
    const unsigned short* __restrict__ dr,
    const unsigned short* __restrict__ wdb, const float* __restrict__ bd,
    float* __restrict__ delta,
    const float* __restrict__ scores, int* __restrict__ sidx)
{
  int bid = blockIdx.x;
  int l = threadIdx.x;
  if(bid < 512){
    int strip = bid >> 3, ct = bid & 7;
    int lr = l & 15, lg = l >> 4;
    int r0 = strip*16;
    const unsigned short* adp = dr + (size_t)(r0+lr)*D + lg*8;
    short8 ad[4];
    #pragma unroll
    for(int s = 0; s < 4; ++s) ad[s] = *(const short8*)(adp + s*32);
    const unsigned short* wd = wdb + (size_t)(ct*16+lr)*D + lg*8;
    floatx4 acc = {0.f,0.f,0.f,0.f};
    #pragma unroll
    for(int s = 0; s < 4; ++s) acc = __builtin_amdgcn_mfma_f32_16x16x32_bf16(ad[s], *(const short8*)(wd + s*32), acc, 0,0,0);
    int col = ct*16 + lr;
    float bdv = bd[col];
    #pragma unroll
    for(int rg = 0; rg < 4; ++rg){
      float d2 = acc[rg] + bdv;
      float sp = (d2 > 20.f) ? d2 : log1pf(expf(d2));
      delta[(size_t)(r0+lg*4+rg)*D + col] = sp;
    }
  } else {
    int i = bid - 512;
    float si = scores[i];
    int c = 0;
    #pragma unroll
    for(int ch = 0; ch < 4; ++ch){
      float4 sj = *(const float4*)&scores[l*4 + ch*256];
      #pragma unroll
      for(int k = 0; k < 4; ++k){
        int j = l*4 + ch*256 + k;
        float s = (k==0)?sj.x:(k==1)?sj.y:(k==2)?sj.z:sj.w;
        c += (s > si || (s == si && j < i)) ? 1 : 0;
      }
    }
    #pragma unroll
    for(int m = 1; m < 64; m <<= 1) c += __shfl_xor(c, m);
    if(l == 0) sidx[c] = i;
  }
}

// ---- cumsum over sorted order: 128 blocks, 1 head/block ----
__global__ __launch_bounds__(1024) void k_cumsum(const float* __restrict__ delta,
     const int* __restrict__ sidx, const float* __restrict__ Bp, float* __restrict__ pfx){
  int t = threadIdx.x, h = blockIdx.x;
  int i = sidx[t];
  float v = delta[(size_t)i*D + h] * Bp[h];
  int lane = t & 63, w = t >> 6;
  #pragma unroll
  for(int o2 = 1; o2 < 64; o2 <<= 1){
    float nb = __shfl_up(v, o2, 64);
    if(lane >= o2) v += nb;
  }
  __shared__ float wsum[16];
  if(lane == 63) wsum[w] = v;
  __syncthreads();
  float pref = 0.f;
  #pragma unroll
  for(int i2 = 0; i2 < 16; ++i2){
    float s = wsum[i2];
    if(i2 < w) pref += s;
  }
  pfx[(size_t)t*D + h] = v + pref;
}

// ---- final: 512 blocks x 256 thr, 2 sorted rows/block; LN + un-permute ----
__global__ __launch_bounds__(256) void k_final(
    const float* __restrict__ delta, const float* __restrict__ res,
    const float* __restrict__ pfx, const int* __restrict__ sidx,
    const float* __restrict__ s1, const float* __restrict__ s2,
    const float* __restrict__ A, const float* __restrict__ Bp,
    const float* __restrict__ Dp, const float* __restrict__ x,
    float* __restrict__ out){
  int b = blockIdx.x, t = threadIdx.x;
  int half = t >> 7, hh = t & 127;
  int l = b*2 + half;
  int i = sidx[l];
  float dlt = delta[(size_t)i*D + hh];
  float dAv = expf(dlt * A[hh]) * Bp[hh];
  float o = dAv * s1[hh] + pfx[(size_t)l*D + hh] * s2[hh] + res[(size_t)i*D + hh] * Dp[0];
  __shared__ float fm[2][2], fv[2][2];
  float v = o;
  v += __shfl_down(v, 32); v += __shfl_down(v, 16); v += __shfl_down(v, 8);
  v += __shfl_down(v, 4);  v += __shfl_down(v, 2);  v += __shfl_down(v, 1);
  int wid = (t >> 6) & 1;
  if((t & 63) == 0) fm[half][wid] = v;
  __syncthreads();
  float mean = (fm[half][0] + fm[half][1]) * (1.0f/128.0f);
  float cd = o - mean;
  float cv = cd*cd;
  cv += __shfl_down(cv, 32); cv += __shfl_down(cv, 16); cv += __shfl_down(cv, 8);
  cv += __shfl_down(cv, 4);  cv += __shfl_down(cv, 2);  cv += __shfl_down(cv, 1);
  if((t & 63) == 0) fv[half][wid] = cv;
  __syncthreads();
  float var = (fv[half][0] + fv[half][1]) * (1.0f/128.0f);
  out[(size_t)i*D + hh] = x[(size_t)i*D + hh] + cd * rsqrtf(var + 1e-5f);
}

} // namespace

extern "C" void kernel_launch(void* const* d_in, const int* in_sizes, int n_in,
                              void* d_out, int out_size, void* d_ws, size_t ws_size,
                              hipStream_t stream){
  const float* x   = (const float*)d_in[0];
  const int*   ei  = (const int*)d_in[1];
  const float* Wl  = (const float*)d_in[2];
  const float* bl  = (const float*)d_in[3];
  const float* Wr  = (const float*)d_in[4];
  const float* W1  = (const float*)d_in[5];
  const float* b1  = (const float*)d_in[6];
  const float* W2  = (const float*)d_in[7];
  const float* b2  = (const float*)d_in[8];
  const float* Wp  = (const float*)d_in[9];
  const float* A   = (const float*)d_in[10];
  const float* Bp  = (const float*)d_in[11];
  const float* Dp  = (const float*)d_in[12];
  const float* Wd  = (const float*)d_in[13];
  const float* bd  = (const float*)d_in[14];

  char* ws = (char*)d_ws;
  size_t o = 0;
  auto alloc = [&](size_t bytes)->char*{
    char* p = ws + o;
    o = (o + bytes + 255) & ~(size_t)255;
    return p;
  };
  float* s1     = (float*)alloc(D*4);
  float* s2     = (float*)alloc(D*4);
  int*   cnt    = (int*)  alloc(N*4);
  int*   srcdeg = (int*)  alloc(N*4);
  int*   bucket = (int*)  alloc((size_t)N*CAP*4);
  float* meanb  = (float*)alloc((size_t)N*D*4);
  unsigned short* xg  = (unsigned short*)alloc((size_t)N*D*2);
  unsigned short* dr  = (unsigned short*)alloc((size_t)N*D*2);
  unsigned short* wlb = (unsigned short*)alloc((size_t)D*D*2);
  unsigned short* wrb = (unsigned short*)alloc((size_t)D*D*2);
  unsigned short* wdb = (unsigned short*)alloc((size_t)D*D*2);
  unsigned short* w1b = (unsigned short*)alloc((size_t)32*D*2);
  unsigned short* wpb = (unsigned short*)alloc((size_t)4*D*D*2);
  float* scores = (float*)alloc(N*4);
  int*   sidx   = (int*)  alloc(N*4);
  float* delta  = (float*)alloc((size_t)N*D*4);
  float* res    = (float*)alloc((size_t)N*D*4);
  float* pfx    = (float*)alloc((size_t)N*D*4);
  (void)ws_size; (void)in_sizes; (void)n_in; (void)out_size;

  k_zero  <<<129, 256, 0, stream>>>(cnt, srcdeg, Wl, Wr, Wd, W1, Wp, wlb, wrb, wdb, w1b, wpb);
  k_edges <<<(E+255)/256, 256, 0, stream>>>(ei, cnt, srcdeg, bucket);
  k_mean  <<<N, 512, 0, stream>>>(x, cnt, bucket, meanb, s1, s2);
  k_g1    <<<64*8, 64, 0, stream>>>(x, meanb, wlb, bl, wrb, xg);
  k_g2    <<<64*25, 64, 0, stream>>>(xg, wpb, w1b, b1, W2, b2, cnt, srcdeg, dr, res, s1, s2, scores);
  k_g3rank<<<512+1024, 64, 0, stream>>>(dr, wdb, bd, delta, scores, sidx);
  k_cumsum<<<D, 1024, 0, stream>>>(delta, sidx, Bp, pfx);
  k_final <<<N/2, 256, 0, stream>>>(delta, res, pfx, sidx, s1, s2, A, Bp, Dp, x, (float*)d_out);
}